// Round 7
// baseline (1032.866 us; speedup 1.0000x reference)
//
#include <hip/hip_runtime.h>
#include <hip/hip_bf16.h>
#include <type_traits>

#define T_ 256
#define B_ 128
#define DIN_ 512
#define H_ 1024
#define DOUT_ 512

typedef __attribute__((ext_vector_type(8))) short bf16x8;
typedef __attribute__((ext_vector_type(4))) short s16x4;
typedef __attribute__((ext_vector_type(4))) float f32x4;
typedef unsigned long long u64;

__device__ inline short f2bf(float f) {
    return __builtin_bit_cast(short, __float2bfloat16(f));
}
__device__ inline float4 zload4(const short* p) {
    u64 u = *(const u64*)p;
    auto bf = [](unsigned x) { return __builtin_bit_cast(float, x << 16); };
    return make_float4(bf((unsigned)(u & 0xffff) ), bf((unsigned)((u >> 16) & 0xffff)),
                       bf((unsigned)((u >> 32) & 0xffff)), bf((unsigned)((u >> 48) & 0xffff)));
}
__device__ inline u64 pack4bf(float v0, float v1, float v2, float v3) {
    return (u64)(unsigned short)f2bf(v0)
         | ((u64)(unsigned short)f2bf(v1) << 16)
         | ((u64)(unsigned short)f2bf(v2) << 32)
         | ((u64)(unsigned short)f2bf(v3) << 48);
}

// Round-7 protocol: SELF-VALIDATING payload, no flags.
//   relu(h) >= 0 -> bf16 sign bit is free. Producer ORs step-parity tag
//   ((t>>1)&1, matching the double-buffer period) into all 4 sign bits of its
//   8B slot (single-thread write -> all-or-nothing). Consumer polls slots
//   until tags match, strips signs, stages to LDS. No flag publish, no flag
//   poll -> 2 fewer LLC round trips per step than round 6. Data stores are
//   plain relaxed sc1 (fire-and-forget is safe: nothing to order against;
//   round-5's store-vs-flag reordering hazard is structurally gone).
//   hbuf memset to 0xAA each launch: sign=1, so t=1/2 consumers (expect tag
//   0) can never accept pre-run garbage; t>=3 is protected by dataflow.
#define AT_LD64(p)    __hip_atomic_load((p), __ATOMIC_RELAXED, __HIP_MEMORY_SCOPE_AGENT)
#define AT_ST64(p, v) __hip_atomic_store((p), (v), __ATOMIC_RELAXED, __HIP_MEMORY_SCOPE_AGENT)

// ---------------------------------------------------------------------------
// Generic GEMM: out[M][N] = A[M][K] * W[N][K]^T + b1 (+ b2), bf16 MFMA.
// (unchanged -- validated rounds 1/3/4/5/6)
// ---------------------------------------------------------------------------
template <typename OUT_T>
__global__ __launch_bounds__(256)
void gemm_bias(const float* __restrict__ A, const float* __restrict__ W,
               const float* __restrict__ b1, const float* __restrict__ b2,
               OUT_T* __restrict__ out, int M, int N, int K)
{
    __shared__ short lA[4096];
    __shared__ short lB[4096];
    const int ntiles = N >> 7;
    const int bm = blockIdx.x / ntiles;
    const int bn = blockIdx.x % ntiles;
    const size_t m0 = (size_t)bm << 7;
    const size_t n0 = (size_t)bn << 7;
    const int tid = threadIdx.x;
    const int w = tid >> 6, l = tid & 63;
    const int wm = (w >> 1) << 6, wn = (w & 1) << 6;

    f32x4 acc[4][4] = {};
    float4 ra[4], rb[4];

    auto load_regs = [&](int k0) {
#pragma unroll
        for (int i = 0; i < 4; ++i) {
            int s = i * 256 + tid;
            int row = s >> 3, kq = s & 7;
            ra[i] = *(const float4*)(A + (m0 + row) * K + k0 + kq * 4);
            rb[i] = *(const float4*)(W + (n0 + row) * K + k0 + kq * 4);
        }
    };
    auto store_lds = [&]() {
#pragma unroll
        for (int i = 0; i < 4; ++i) {
            int s = i * 256 + tid;
            int row = s >> 3, kq = s & 7;
            int off = ((row >> 4) * 64 + ((row & 15) | ((kq >> 1) << 4))) * 8 + (kq & 1) * 4;
            s16x4 pa = { f2bf(ra[i].x), f2bf(ra[i].y), f2bf(ra[i].z), f2bf(ra[i].w) };
            s16x4 pb = { f2bf(rb[i].x), f2bf(rb[i].y), f2bf(rb[i].z), f2bf(rb[i].w) };
            *(s16x4*)&lA[off] = pa;
            *(s16x4*)&lB[off] = pb;
        }
    };

    load_regs(0);
    const int KI = K >> 5;
    for (int ki = 0; ki < KI; ++ki) {
        __syncthreads();
        store_lds();
        __syncthreads();
        if (ki + 1 < KI) load_regs((ki + 1) << 5);
        bf16x8 aF[4], bF[4];
#pragma unroll
        for (int i = 0; i < 4; ++i) {
            aF[i] = *(const bf16x8*)&lA[(((wm >> 4) + i) * 64 + l) * 8];
            bF[i] = *(const bf16x8*)&lB[(((wn >> 4) + i) * 64 + l) * 8];
        }
#pragma unroll
        for (int i = 0; i < 4; ++i)
#pragma unroll
            for (int j = 0; j < 4; ++j)
                acc[i][j] = __builtin_amdgcn_mfma_f32_16x16x32_bf16(aF[i], bF[j], acc[i][j], 0, 0, 0);
    }

#pragma unroll
    for (int j = 0; j < 4; ++j) {
        const int col = (int)n0 + wn + j * 16 + (l & 15);
        float bb = b1[col];
        if (b2) bb += b2[col];
#pragma unroll
        for (int i = 0; i < 4; ++i) {
#pragma unroll
            for (int r = 0; r < 4; ++r) {
                int row = (int)m0 + wm + i * 16 + (l >> 4) * 4 + r;
                float v = acc[i][j][r] + bb;
                if constexpr (std::is_same<OUT_T, short>::value)
                    out[(size_t)row * N + col] = f2bf(v);
                else
                    out[(size_t)row * N + col] = v;
            }
        }
    }
}

// ---------------------------------------------------------------------------
// Recurrence v7 = v6 structure + sign-parity tagged hbuf (flag-free).
//   128 WGs = 8 bg (16 batch rows) x 16 cg (64 cols), 256 thr (4 waves).
//   Wave owns 16 cols: wh[32] (A-frag) resident in the register file.
//   Per step: poll-stage bg's h(t-1) (32 KB, B-frag, tag-validated)
//   LLC->LDS, K-loop = ds_read_b128 + MFMA (2 chains), epilogue ->
//   hidden (f32, plain) + hbuf (tagged bf16, relaxed sc1 store).
// ---------------------------------------------------------------------------
__global__ __launch_bounds__(256, 1)
void rnn_rec7(const short* __restrict__ zi, const float* __restrict__ Wh,
              float* __restrict__ hidden, unsigned short* __restrict__ hbuf)
{
    const int wg = blockIdx.x;           // 0..127
    const int bg = wg >> 4, cg = wg & 15;
    const int tid = threadIdx.x, w = tid >> 6, l = tid & 63;
    const int b = l & 15, hi = l >> 4;
    const int ocw = cg * 64 + w * 16;    // wave's 16 output columns
    const u64 SIGN = 0x8000800080008000ull;

    __shared__ u64 lds_h[4096];          // 32 KB: bg's h tile, B-frag layout

    // ---- Wh -> registers (A-frag: oc = ocw + (l&15), k = kk*32 + hi*8 + j) ----
    bf16x8 wh[32];
#pragma unroll
    for (int kk = 0; kk < 32; ++kk) {
        const float* wp = Wh + (size_t)(ocw + b) * H_ + kk * 32 + hi * 8;
        float4 a = *(const float4*)wp;
        float4 c = *(const float4*)(wp + 4);
        bf16x8 v = { f2bf(a.x), f2bf(a.y), f2bf(a.z), f2bf(a.w),
                     f2bf(c.x), f2bf(c.y), f2bf(c.z), f2bf(c.w) };
        wh[kk] = v;
    }

    // zi: batch row = bg*16 + b, cols f0 = ocw + hi*4 .. +3
    const int f0 = ocw + hi * 4;
    float4 z = zload4(zi + ((size_t)bg * 16 + b) * H_ + f0);

    // hbuf-store address bits (B-frag: kk2 = c>>5, lane2 = b | (((c>>3)&3)<<4), j0 = c&7)
    const int kk2 = f0 >> 5, j0 = f0 & 7;
    const int lane2 = b | (((f0 >> 3) & 3) << 4);

#pragma unroll 1
    for (int t = 0; t < T_; ++t) {
        const size_t zb = (size_t)t * B_ * H_;
        f32x4 acc0 = {}, acc1 = {};
        if (t > 0) {
            // ---- poll-stage h(t-1): tags must match ((t-1)>>1)&1 ----
            const u64 expmask = (((t - 1) >> 1) & 1) ? SIGN : 0ull;
            const u64* hp = (const u64*)hbuf + (size_t)(((t + 1) & 1) * 8 + bg) * 4096;
            u64 sv[16];
#pragma unroll
            for (int i = 0; i < 16; ++i)
                sv[i] = AT_LD64(hp + i * 256 + tid);
            unsigned pend = 0xFFFFu;
            while (pend) {
#pragma unroll
                for (int i = 0; i < 16; ++i) {
                    if (pend & (1u << i)) {
                        if ((sv[i] & SIGN) == expmask) pend &= ~(1u << i);
                        else sv[i] = AT_LD64(hp + i * 256 + tid);
                    }
                }
            }
            if (expmask) {                // strip tag bits (only set when tag==1)
#pragma unroll
                for (int i = 0; i < 16; ++i) sv[i] &= ~SIGN;
            }
#pragma unroll
            for (int i = 0; i < 16; ++i)
                lds_h[i * 256 + tid] = sv[i];
            __syncthreads();
            // ---- K-loop: pure LDS + MFMA, 2 chains ----
#pragma unroll
            for (int kk = 0; kk < 32; ++kk) {
                bf16x8 hbf = *(const bf16x8*)&lds_h[(kk * 64 + l) * 2];
                if (kk & 1)
                    acc1 = __builtin_amdgcn_mfma_f32_16x16x32_bf16(wh[kk], hbf, acc1, 0, 0, 0);
                else
                    acc0 = __builtin_amdgcn_mfma_f32_16x16x32_bf16(wh[kk], hbf, acc0, 0, 0, 0);
            }
        }
        // ---- epilogue: relu(acc + zi) -> hidden (plain f32x4) + hbuf (tagged) ----
        float v0 = fmaxf(acc0[0] + acc1[0] + z.x, 0.f);
        float v1 = fmaxf(acc0[1] + acc1[1] + z.y, 0.f);
        float v2 = fmaxf(acc0[2] + acc1[2] + z.z, 0.f);
        float v3 = fmaxf(acc0[3] + acc1[3] + z.w, 0.f);
        *(float4*)(hidden + zb + (size_t)(bg * 16 + b) * H_ + f0) =
            make_float4(v0, v1, v2, v3);
        unsigned short* hwS = hbuf + (size_t)((t & 1) * 8 + bg) * 16384;
        u64 payload = pack4bf(v0, v1, v2, v3) | (((t >> 1) & 1) ? SIGN : 0ull);
        AT_ST64((u64*)(hwS + (kk2 * 64 + lane2) * 8 + j0), payload);

        if (t + 1 < T_)                   // prefetch zi(t+1); hides under next poll
            z = zload4(zi + ((size_t)(t + 1) * B_ + bg * 16 + b) * H_ + f0);

        __syncthreads();                  // LDS WAR: K-loop reads done before next stage
    }
}

__global__ __launch_bounds__(256)
void copy_k(const float4* __restrict__ s, float4* __restrict__ d)
{
    int i = blockIdx.x * 256 + threadIdx.x;
    d[i] = s[i];
}

extern "C" void kernel_launch(void* const* d_in, const int* in_sizes, int n_in,
                              void* d_out, int out_size, void* d_ws, size_t ws_size,
                              hipStream_t stream)
{
    const float* x  = (const float*)d_in[0];
    const float* Wi = (const float*)d_in[1];
    const float* bi = (const float*)d_in[2];
    const float* Wh = (const float*)d_in[3];
    const float* bh = (const float*)d_in[4];
    const float* Wo = (const float*)d_in[5];
    const float* bo = (const float*)d_in[6];

    float* hidden = (float*)d_out;                       // [T][B][H]
    float* hT     = hidden + (size_t)T_ * B_ * H_;       // [B][H]
    float* y      = hT + (size_t)B_ * H_;                // [T][B][O]

    const size_t HBUF_B = (size_t)2 * B_ * H_ * sizeof(short);   // 512 KB
    const size_t ZI_B   = (size_t)T_ * B_ * H_ * sizeof(short);  // 64 MB (bf16)

    short* zi;
    unsigned short* hbuf;
    if (ws_size >= HBUF_B + ZI_B) {
        hbuf = (unsigned short*)d_ws;
        zi   = (short*)((char*)d_ws + HBUF_B);
    } else {
        // zi (bf16) in y-section; hbuf in hT-section (both overwritten later)
        zi   = (short*)y;
        hbuf = (unsigned short*)hT;
    }

    // 0xAA pattern: every bf16 slot has sign=1 -> can never satisfy the t=1/2
    // consumers (expect tag 0). Deterministic across graph replays.
    hipMemsetAsync(hbuf, 0xAA, HBUF_B, stream);

    gemm_bias<short><<<dim3(2048), dim3(256), 0, stream>>>(
        x, Wi, bi, bh, zi, T_ * B_, H_, DIN_);
    rnn_rec7<<<dim3(128), dim3(256), 0, stream>>>(zi, Wh, hidden, hbuf);

    // hT = hidden[T-1]
    copy_k<<<dim3(128), dim3(256), 0, stream>>>(
        (const float4*)(hidden + (size_t)(T_ - 1) * B_ * H_), (float4*)hT);

    // y = hidden @ Wo^T + bo
    gemm_bias<float><<<dim3(1024), dim3(256), 0, stream>>>(
        hidden, Wo, bo, nullptr, y, T_ * B_, DOUT_, H_);
}

// Round 9
// 1019.696 us; speedup vs baseline: 1.0129x; 1.0129x over previous
//
#include <hip/hip_runtime.h>
#include <hip/hip_bf16.h>
#include <type_traits>

#define T_ 256
#define B_ 128
#define DIN_ 512
#define H_ 1024
#define DOUT_ 512

typedef __attribute__((ext_vector_type(8))) short bf16x8;
typedef __attribute__((ext_vector_type(4))) short s16x4;
typedef __attribute__((ext_vector_type(4))) float f32x4;
typedef unsigned long long u64;

__device__ unsigned g_flags[2048];   // 128 cg-counters x 16-uint stride; zeroed per launch

__device__ inline short f2bf(float f) {
    return __builtin_bit_cast(short, __float2bfloat16(f));
}
__device__ inline float4 zload4(const short* p) {
    u64 u = *(const u64*)p;
    auto bf = [](unsigned x) { return __builtin_bit_cast(float, x << 16); };
    return make_float4(bf((unsigned)(u & 0xffff) ), bf((unsigned)((u >> 16) & 0xffff)),
                       bf((unsigned)((u >> 32) & 0xffff)), bf((unsigned)((u >> 48) & 0xffff)));
}
__device__ inline u64 pack4bf(float v0, float v1, float v2, float v3) {
    return (u64)(unsigned short)f2bf(v0)
         | ((u64)(unsigned short)f2bf(v1) << 16)
         | ((u64)(unsigned short)f2bf(v2) << 32)
         | ((u64)(unsigned short)f2bf(v3) << 48);
}

// All cross-WG primitives are the round-6-VALIDATED ones:
//   data + counters: relaxed agent-scope RMW (executes AT the LLC; ack ==
//   executed) for producers; relaxed agent loads (read LLC) for consumers.
#define AT_LD64(p)     __hip_atomic_load((p), __ATOMIC_RELAXED, __HIP_MEMORY_SCOPE_AGENT)
#define AT_SWP64(p, v) (void)__hip_atomic_exchange((p), (v), __ATOMIC_RELAXED, __HIP_MEMORY_SCOPE_AGENT)
#define AT_LD32(p)     __hip_atomic_load((p), __ATOMIC_RELAXED, __HIP_MEMORY_SCOPE_AGENT)
#define AT_ADD32(p, v) (void)__hip_atomic_fetch_add((p), (v), __ATOMIC_RELAXED, __HIP_MEMORY_SCOPE_AGENT)

__global__ void zero_flags() { g_flags[blockIdx.x * 256 + threadIdx.x] = 0; }

// ---------------------------------------------------------------------------
// Generic GEMM: out[M][N] = A[M][K] * W[N][K]^T + b1 (+ b2), bf16 MFMA.
// (unchanged -- validated rounds 1/3/4/5/6/7)
// ---------------------------------------------------------------------------
template <typename OUT_T>
__global__ __launch_bounds__(256)
void gemm_bias(const float* __restrict__ A, const float* __restrict__ W,
               const float* __restrict__ b1, const float* __restrict__ b2,
               OUT_T* __restrict__ out, int M, int N, int K)
{
    __shared__ short lA[4096];
    __shared__ short lB[4096];
    const int ntiles = N >> 7;
    const int bm = blockIdx.x / ntiles;
    const int bn = blockIdx.x % ntiles;
    const size_t m0 = (size_t)bm << 7;
    const size_t n0 = (size_t)bn << 7;
    const int tid = threadIdx.x;
    const int w = tid >> 6, l = tid & 63;
    const int wm = (w >> 1) << 6, wn = (w & 1) << 6;

    f32x4 acc[4][4] = {};
    float4 ra[4], rb[4];

    auto load_regs = [&](int k0) {
#pragma unroll
        for (int i = 0; i < 4; ++i) {
            int s = i * 256 + tid;
            int row = s >> 3, kq = s & 7;
            ra[i] = *(const float4*)(A + (m0 + row) * K + k0 + kq * 4);
            rb[i] = *(const float4*)(W + (n0 + row) * K + k0 + kq * 4);
        }
    };
    auto store_lds = [&]() {
#pragma unroll
        for (int i = 0; i < 4; ++i) {
            int s = i * 256 + tid;
            int row = s >> 3, kq = s & 7;
            int off = ((row >> 4) * 64 + ((row & 15) | ((kq >> 1) << 4))) * 8 + (kq & 1) * 4;
            s16x4 pa = { f2bf(ra[i].x), f2bf(ra[i].y), f2bf(ra[i].z), f2bf(ra[i].w) };
            s16x4 pb = { f2bf(rb[i].x), f2bf(rb[i].y), f2bf(rb[i].z), f2bf(rb[i].w) };
            *(s16x4*)&lA[off] = pa;
            *(s16x4*)&lB[off] = pb;
        }
    };

    load_regs(0);
    const int KI = K >> 5;
    for (int ki = 0; ki < KI; ++ki) {
        __syncthreads();
        store_lds();
        __syncthreads();
        if (ki + 1 < KI) load_regs((ki + 1) << 5);
        bf16x8 aF[4], bF[4];
#pragma unroll
        for (int i = 0; i < 4; ++i) {
            aF[i] = *(const bf16x8*)&lA[(((wm >> 4) + i) * 64 + l) * 8];
            bF[i] = *(const bf16x8*)&lB[(((wn >> 4) + i) * 64 + l) * 8];
        }
#pragma unroll
        for (int i = 0; i < 4; ++i)
#pragma unroll
            for (int j = 0; j < 4; ++j)
                acc[i][j] = __builtin_amdgcn_mfma_f32_16x16x32_bf16(aF[i], bF[j], acc[i][j], 0, 0, 0);
    }

#pragma unroll
    for (int j = 0; j < 4; ++j) {
        const int col = (int)n0 + wn + j * 16 + (l & 15);
        float bb = b1[col];
        if (b2) bb += b2[col];
#pragma unroll
        for (int i = 0; i < 4; ++i) {
#pragma unroll
            for (int r = 0; r < 4; ++r) {
                int row = (int)m0 + wm + i * 16 + (l >> 4) * 4 + r;
                float v = acc[i][j][r] + bb;
                if constexpr (std::is_same<OUT_T, short>::value)
                    out[(size_t)row * N + col] = f2bf(v);
                else
                    out[(size_t)row * N + col] = v;
            }
        }
    }
}

// ---------------------------------------------------------------------------
// Recurrence v9 = v6 protocol, critical path tightened:
//   (1) per-wave counter publish: each wave vmcnt(0)-drains its OWN swaps
//       then fetch_add(+1) on its cg counter; consumer target = 4*(t+1).
//       Safe: no wave can issue a step-(t+1) add before the step-t barrier,
//       and every drain precedes its add, so the counter cannot reach
//       4(t+1) until ALL waves' step-t swaps are LLC-executed.
//   (2) speculative staging w/ sign-parity tags (relu(h) >= 0, sign free):
//       issue the 16 next-buffer loads right after publishing, overlap
//       their latency with the poll; after the barrier, re-load only slots
//       whose tag mismatches (flags confirmed => re-load is fresh).
//       Spec only for steps >= 3 (earlier: pre-run slot contents could
//       alias tags); steps 1-2 stage post-flag as in v6.
// ---------------------------------------------------------------------------
__global__ __launch_bounds__(256, 1)
void rnn_rec9(const short* __restrict__ zi, const float* __restrict__ Wh,
              float* __restrict__ hidden, unsigned short* __restrict__ hbuf)
{
    const int wg = blockIdx.x;           // 0..127
    const int bg = wg >> 4, cg = wg & 15;
    const int tid = threadIdx.x, w = tid >> 6, l = tid & 63;
    const int b = l & 15, hi = l >> 4;
    const int ocw = cg * 64 + w * 16;    // wave's 16 output columns
    const u64 SIGN = 0x8000800080008000ull;

    __shared__ u64 lds_h[4096];          // 32 KB: bg's h tile, B-frag layout

    // ---- Wh -> registers (A-frag: oc = ocw + (l&15), k = kk*32 + hi*8 + j) ----
    bf16x8 wh[32];
#pragma unroll
    for (int kk = 0; kk < 32; ++kk) {
        const float* wp = Wh + (size_t)(ocw + b) * H_ + kk * 32 + hi * 8;
        float4 a = *(const float4*)wp;
        float4 c = *(const float4*)(wp + 4);
        bf16x8 v = { f2bf(a.x), f2bf(a.y), f2bf(a.z), f2bf(a.w),
                     f2bf(c.x), f2bf(c.y), f2bf(c.z), f2bf(c.w) };
        wh[kk] = v;
    }

    const int f0 = ocw + hi * 4;
    float4 z = zload4(zi + ((size_t)bg * 16 + b) * H_ + f0);

    // hbuf slot bits (B-frag: kk2 = c>>5, lane2 = b | (((c>>3)&3)<<4), j0 = c&7)
    const int kk2 = f0 >> 5, j0 = f0 & 7;
    const int lane2 = b | (((f0 >> 3) & 3) << 4);

    u64 sv[16];                          // staged h slots (spec or post-flag)

#pragma unroll 1
    for (int t = 0; t < T_; ++t) {
        const size_t zb = (size_t)t * B_ * H_;
        f32x4 acc0 = {}, acc1 = {};
        if (t > 0) {
            const u64 expmask = (((t - 1) >> 1) & 1) ? SIGN : 0ull;
            const u64* hp = (const u64*)hbuf + (size_t)(((t + 1) & 1) * 8 + bg) * 4096;
            if (t >= 3) {
                // sv[] was speculatively loaded at end of step t-1.
                // Flags are confirmed -> any tag-mismatched slot re-loads fresh.
#pragma unroll
                for (int i = 0; i < 16; ++i)
                    if ((sv[i] & SIGN) != expmask)
                        sv[i] = AT_LD64(hp + i * 256 + tid);
            } else {
                // steps 1-2: non-speculative post-flag stage (v6 path)
#pragma unroll
                for (int i = 0; i < 16; ++i)
                    sv[i] = AT_LD64(hp + i * 256 + tid);
            }
            if (expmask) {               // strip tag bits (set only on odd parity)
#pragma unroll
                for (int i = 0; i < 16; ++i) sv[i] &= ~SIGN;
            }
#pragma unroll
            for (int i = 0; i < 16; ++i)
                lds_h[i * 256 + tid] = sv[i];
            __syncthreads();
            // ---- K-loop: pure LDS + MFMA, 2 chains ----
#pragma unroll
            for (int kk = 0; kk < 32; ++kk) {
                bf16x8 hbf = *(const bf16x8*)&lds_h[(kk * 64 + l) * 2];
                if (kk & 1)
                    acc1 = __builtin_amdgcn_mfma_f32_16x16x32_bf16(wh[kk], hbf, acc1, 0, 0, 0);
                else
                    acc0 = __builtin_amdgcn_mfma_f32_16x16x32_bf16(wh[kk], hbf, acc0, 0, 0, 0);
            }
        }
        // ---- epilogue: relu(acc + zi) -> hidden (plain) + hbuf (tagged RMW) ----
        float v0 = fmaxf(acc0[0] + acc1[0] + z.x, 0.f);
        float v1 = fmaxf(acc0[1] + acc1[1] + z.y, 0.f);
        float v2 = fmaxf(acc0[2] + acc1[2] + z.z, 0.f);
        float v3 = fmaxf(acc0[3] + acc1[3] + z.w, 0.f);
        *(float4*)(hidden + zb + (size_t)(bg * 16 + b) * H_ + f0) =
            make_float4(v0, v1, v2, v3);
        unsigned short* hwS = hbuf + (size_t)((t & 1) * 8 + bg) * 16384;
        u64 pay = pack4bf(v0, v1, v2, v3) | (((t >> 1) & 1) ? SIGN : 0ull);
        AT_SWP64((u64*)(hwS + (kk2 * 64 + lane2) * 8 + j0), pay);

        // ---- per-wave publish: drain OWN swaps, then +1 on this cg's counter ----
        asm volatile("s_waitcnt vmcnt(0)" ::: "memory");
        __builtin_amdgcn_sched_barrier(0);
        if (l == 0)
            AT_ADD32(&g_flags[(bg * 16 + cg) * 16], 1u);

        if (t + 1 < T_) {
            // prefetch zi(t+1)
            z = zload4(zi + ((size_t)(t + 1) * B_ + bg * 16 + b) * H_ + f0);
            // speculative issue of next stage (overlaps the poll below)
            if (t + 1 >= 3) {
                const u64* hpn = (const u64*)hbuf + (size_t)((t & 1) * 8 + bg) * 4096;
#pragma unroll
                for (int i = 0; i < 16; ++i)
                    sv[i] = AT_LD64(hpn + i * 256 + tid);
            }
            if (w == 0) {                // wave 0 polls this bg's 16 cg counters
                const unsigned tgt = 4u * (unsigned)(t + 1);
                const unsigned* fp = &g_flags[(bg * 16 + (l & 15)) * 16];
                unsigned fv;
                do {
                    fv = AT_LD32(fp);
                } while (!__all((int)(fv >= tgt)));
            }
        }
        __syncthreads();
    }
}

__global__ __launch_bounds__(256)
void copy_k(const float4* __restrict__ s, float4* __restrict__ d)
{
    int i = blockIdx.x * 256 + threadIdx.x;
    d[i] = s[i];
}

extern "C" void kernel_launch(void* const* d_in, const int* in_sizes, int n_in,
                              void* d_out, int out_size, void* d_ws, size_t ws_size,
                              hipStream_t stream)
{
    const float* x  = (const float*)d_in[0];
    const float* Wi = (const float*)d_in[1];
    const float* bi = (const float*)d_in[2];
    const float* Wh = (const float*)d_in[3];
    const float* bh = (const float*)d_in[4];
    const float* Wo = (const float*)d_in[5];
    const float* bo = (const float*)d_in[6];

    float* hidden = (float*)d_out;                       // [T][B][H]
    float* hT     = hidden + (size_t)T_ * B_ * H_;       // [B][H]
    float* y      = hT + (size_t)B_ * H_;                // [T][B][O]

    const size_t HBUF_B = (size_t)2 * B_ * H_ * sizeof(short);   // 512 KB
    const size_t ZI_B   = (size_t)T_ * B_ * H_ * sizeof(short);  // 64 MB (bf16)

    zero_flags<<<dim3(8), dim3(256), 0, stream>>>();

    short* zi;
    unsigned short* hbuf;
    if (ws_size >= HBUF_B + ZI_B) {
        hbuf = (unsigned short*)d_ws;
        zi   = (short*)((char*)d_ws + HBUF_B);
    } else {
        // zi (bf16) in y-section; hbuf in hT-section (both overwritten later)
        zi   = (short*)y;
        hbuf = (unsigned short*)hT;
    }

    gemm_bias<short><<<dim3(2048), dim3(256), 0, stream>>>(
        x, Wi, bi, bh, zi, T_ * B_, H_, DIN_);
    rnn_rec9<<<dim3(128), dim3(256), 0, stream>>>(zi, Wh, hidden, hbuf);

    // hT = hidden[T-1]
    copy_k<<<dim3(128), dim3(256), 0, stream>>>(
        (const float4*)(hidden + (size_t)(T_ - 1) * B_ * H_), (float4*)hT);

    // y = hidden @ Wo^T + bo
    gemm_bias<float><<<dim3(1024), dim3(256), 0, stream>>>(
        hidden, Wo, bo, nullptr, y, T_ * B_, DOUT_, H_);
}